// Round 7
// baseline (77.086 us; speedup 1.0000x reference)
//
#include <hip/hip_runtime.h>
#include <float.h>

#define OUTP 7
#define NCH 256
#define FH 50
#define FW 50
#define CHW (FH * FW)

__device__ __forceinline__ float shfl_xor_f(float v, int mask) {
    return __shfl_xor(v, mask, 64);
}

// One wave per (roi, channel). Per row-bin: 2D lane tile (row-slot x float2
// chunk) loads the whole bin in 1-4 dwordx2 instructions (clamped duplicate
// rows/chunks coalesce inside the instruction); in-register shfl_xor
// butterfly folds row slots; lanes<wp write per-column bin maxima to LDS.
// No __syncthreads: rowmax dataflow is intra-wave (wave64 lockstep).
// float2 chunks [x1>>1 .. x2>>1] never cross the feature-row end -> no OOB,
// no masking; garbage columns land at unconsumed rowmax positions.
__global__ __launch_bounds__(256) void roi_pool_v7(
    const float* __restrict__ features,   // (B,256,50,50)
    const float* __restrict__ cat_rois,   // (N,5): im,x1,y1,x2,y2
    float* __restrict__ out)              // (N,256,7,7)
{
    __shared__ float rowmax[4][OUTP][66];   // per-wave slice, 7392 B

    const int lane = threadIdx.x & 63;
    const int quad = threadIdx.x >> 6;
    const int n    = blockIdx.x >> 6;                 // 64 blocks per ROI
    const int c    = ((blockIdx.x & 63) << 2) + quad; // 4 ch per block

    const float* r5 = cat_rois + n * 5;
    const int im = __builtin_amdgcn_readfirstlane((int)rintf(r5[0]));
    const int x1 = __builtin_amdgcn_readfirstlane((int)rintf(r5[1] * 0.0625f));
    const int y1 = __builtin_amdgcn_readfirstlane((int)rintf(r5[2] * 0.0625f));
    const int x2 = __builtin_amdgcn_readfirstlane((int)rintf(r5[3] * 0.0625f));
    const int y2 = __builtin_amdgcn_readfirstlane((int)rintf(r5[4] * 0.0625f));

    const int h   = y2 - y1 + 1;
    const int w   = x2 - x1 + 1;
    const int cs2 = x1 >> 1;
    const int nck = (x2 >> 1) - cs2 + 1;      // 1..26 float2 chunks

    // wave-uniform tier: wp chunk-lanes x rpt row-slots = 64
    const int shift = (nck <= 8) ? 3 : (nck <= 16) ? 4 : 5;
    const int wp    = 1 << shift;             // 8 / 16 / 32
    const int rpt   = 64 >> shift;            // 8 / 4  / 2
    const int c4    = lane & (wp - 1);
    const int rsub  = lane >> shift;

    const int ck = cs2 + min(c4, nck - 1);    // clamped chunk, in-row safe
    const float* base = features + (size_t)(im * NCH + c) * CHW + ck * 2;

    #pragma unroll
    for (int i = 0; i < OUTP; ++i) {
        const int ys  = i * h / OUTP;                                // SALU
        const int bh1 = ((i + 1) * h + OUTP - 1) / OUTP - 1 - ys;    // 0..7

        float mx, my;
        {
            const int rr = y1 + ys + min(rsub, bh1);
            const float2 v = *(const float2*)(base + rr * FW);
            mx = v.x; my = v.y;
        }
        if (shift >= 4) {                       // tiers B,C: 2nd row pass
            const int rr = y1 + ys + min(rsub + rpt, bh1);
            const float2 v = *(const float2*)(base + rr * FW);
            mx = fmaxf(mx, v.x); my = fmaxf(my, v.y);
            if (shift == 5) {                   // tier C: passes 3,4
                const int ra = y1 + ys + min(rsub + 2 * rpt, bh1);
                const int rb = y1 + ys + min(rsub + 3 * rpt, bh1);
                const float2 va = *(const float2*)(base + ra * FW);
                const float2 vb = *(const float2*)(base + rb * FW);
                mx = fmaxf(mx, fmaxf(va.x, vb.x));
                my = fmaxf(my, fmaxf(va.y, vb.y));
            }
        }

        // butterfly fold across row slots (xor masks >= wp keep c4 intact)
        mx = fmaxf(mx, shfl_xor_f(mx, 32));
        my = fmaxf(my, shfl_xor_f(my, 32));
        if (shift <= 4) {
            mx = fmaxf(mx, shfl_xor_f(mx, 16));
            my = fmaxf(my, shfl_xor_f(my, 16));
        }
        if (shift <= 3) {
            mx = fmaxf(mx, shfl_xor_f(mx, 8));
            my = fmaxf(my, shfl_xor_f(my, 8));
        }

        if (lane < wp) {                        // rsub==0 slice
            rowmax[quad][i][2 * c4]     = mx;
            rowmax[quad][i][2 * c4 + 1] = my;
        }
    }

    __threadfence_block();   // lgkm drain; intra-wave LDS RAW, no barrier

    if (lane < OUTP * OUTP) {
        const int i   = lane / OUTP;
        const int j   = lane - i * OUTP;
        const int d   = x1 & 1;                 // col offset inside chunk grid
        const int xs  = j * w / OUTP + d;
        const int xe1 = ((j + 1) * w + OUTP - 1) / OUTP - 1 + d;  // >= xs
        const float* rp = rowmax[quad][i];
        float m = rp[xs];
        #pragma unroll
        for (int k = 1; k < 8; ++k)             // bin width <= 8, clamped
            m = fmaxf(m, rp[min(xs + k, xe1)]);
        out[((size_t)n * NCH + c) * (OUTP * OUTP) + lane] = m;
    }
}

extern "C" void kernel_launch(void* const* d_in, const int* in_sizes, int n_in,
                              void* d_out, int out_size, void* d_ws, size_t ws_size,
                              hipStream_t stream) {
    const float* features = (const float*)d_in[0];
    const float* cat_rois = (const float*)d_in[1];
    float* out = (float*)d_out;

    const int N = in_sizes[1] / 5;        // 128 ROIs
    dim3 grid(N * (NCH / 4));             // 8192 blocks, 4 waves each
    roi_pool_v7<<<grid, 256, 0, stream>>>(features, cat_rois, out);
}

// Round 8
// 73.659 us; speedup vs baseline: 1.0465x; 1.0465x over previous
//
#include <hip/hip_runtime.h>
#include <float.h>

#define OUTP 7
#define NCH 256
#define FH 50
#define FW 50
#define LDS_W 65   // 64 lanes + 1 pad

// FINAL (revert to v5, best measured: 73.6 us total vs 52 us harness floor).
// One wave per (roi, channel). Lane = column within ROI region.
// Fixed clamped-unroll per row-bin: bin height <= 4 rows (h<=21) or <= 8 rows
// (h<=50), proven by size = ceil((i+1)h/7)-floor(ih/7) <= floor((h+5)/7)+1.
// Clamped duplicate rows re-load the same address (L1 broadcast, ~free) in
// exchange for 28-56 fully independent loads in flight.
// readfirstlane forces ROI params to SGPRs: bound math + row addressing on
// the scalar pipe. Evidence v5/v6/v7 (issue-count, vmem-count, wave-count
// all varied 3-4x, total invariant 73.6-77.1): remaining time is harness
// fill + launch/latency floor, not kernel-shape-dependent.
__global__ __launch_bounds__(256) void roi_pool_v5(
    const float* __restrict__ features,   // (B,256,50,50)
    const float* __restrict__ cat_rois,   // (N,5): im,x1,y1,x2,y2
    float* __restrict__ out)              // (N,256,7,7)
{
    __shared__ float rowmax[4][OUTP][LDS_W];   // 7280 B

    const int lane = threadIdx.x & 63;
    const int quad = threadIdx.x >> 6;         // wave id in block
    const int n    = blockIdx.x >> 6;          // 64 blocks per ROI
    const int c    = ((blockIdx.x & 63) << 2) + quad;

    const float* r5 = cat_rois + n * 5;
    const int im = __builtin_amdgcn_readfirstlane((int)rintf(r5[0]));
    const int x1 = __builtin_amdgcn_readfirstlane((int)rintf(r5[1] * 0.0625f));
    const int y1 = __builtin_amdgcn_readfirstlane((int)rintf(r5[2] * 0.0625f));
    const int x2 = __builtin_amdgcn_readfirstlane((int)rintf(r5[3] * 0.0625f));
    const int y2 = __builtin_amdgcn_readfirstlane((int)rintf(r5[4] * 0.0625f));

    const int h = y2 - y1 + 1;   // region fully in-bounds (clamps are no-ops)
    const int w = x2 - x1 + 1;

    const float* base = features + ((size_t)(im * NCH + c)) * (FH * FW)
                                 + y1 * FW + x1;

    float rm[OUTP];
    #pragma unroll
    for (int i = 0; i < OUTP; ++i) rm[i] = -FLT_MAX;

    if (lane < w) {
        if (h <= 21) {
            // bin height <= 4: fixed 4 clamped loads per bin, all independent
            #pragma unroll
            for (int i = 0; i < OUTP; ++i) {
                const int ys  = i * h / OUTP;                        // SALU
                const int ye1 = ((i + 1) * h + OUTP - 1) / OUTP - 1; // >= ys
                float v0 = base[ys * FW + lane];
                float v1 = base[min(ys + 1, ye1) * FW + lane];
                float v2 = base[min(ys + 2, ye1) * FW + lane];
                float v3 = base[min(ys + 3, ye1) * FW + lane];
                rm[i] = fmaxf(fmaxf(v0, v1), fmaxf(v2, v3));
            }
        } else {
            // h in (21,50]: bin height <= 8
            #pragma unroll
            for (int i = 0; i < OUTP; ++i) {
                const int ys  = i * h / OUTP;
                const int ye1 = ((i + 1) * h + OUTP - 1) / OUTP - 1;
                float v[8];
                #pragma unroll
                for (int k = 0; k < 8; ++k)
                    v[k] = base[min(ys + k, ye1) * FW + lane];
                float m01 = fmaxf(v[0], v[1]), m23 = fmaxf(v[2], v[3]);
                float m45 = fmaxf(v[4], v[5]), m67 = fmaxf(v[6], v[7]);
                rm[i] = fmaxf(fmaxf(m01, m23), fmaxf(m45, m67));
            }
        }
    }

    #pragma unroll
    for (int i = 0; i < OUTP; ++i)
        rowmax[quad][i][lane] = rm[i];

    __syncthreads();

    // 49 lanes col-pool from LDS (~3 reads avg, <=8)
    if (lane < OUTP * OUTP) {
        const int i  = lane / OUTP;
        const int j  = lane % OUTP;
        const int xs = j * w / OUTP;
        const int xe = ((j + 1) * w + OUTP - 1) / OUTP;   // <= w always

        float m = -FLT_MAX;
        for (int x = xs; x < xe; ++x)
            m = fmaxf(m, rowmax[quad][i][x]);

        out[(((size_t)n * NCH + c) * OUTP + i) * OUTP + j] = m;
    }
}

extern "C" void kernel_launch(void* const* d_in, const int* in_sizes, int n_in,
                              void* d_out, int out_size, void* d_ws, size_t ws_size,
                              hipStream_t stream) {
    const float* features = (const float*)d_in[0];
    const float* cat_rois = (const float*)d_in[1];
    float* out = (float*)d_out;

    const int N = in_sizes[1] / 5;        // 128 ROIs
    dim3 grid(N * (NCH / 4));             // 8192 blocks, 4 waves each
    roi_pool_v5<<<grid, 256, 0, stream>>>(features, cat_rois, out);
}